// Round 1
// baseline (656.154 us; speedup 1.0000x reference)
//
#include <hip/hip_runtime.h>
#include <hip/hip_bf16.h>

typedef __attribute__((ext_vector_type(8))) short bf16x8;
typedef __attribute__((ext_vector_type(4))) float f32x4;

#define HDIM 512
#define BM 128
#define BN 128
#define BK 64
#define BKP 72   // +8 bf16 pad -> row stride 144 B (16B-aligned, 4-bank rotation)

__device__ __forceinline__ unsigned short f2bf(float f) {
  unsigned u = __float_as_uint(f);
  u += 0x7fffu + ((u >> 16) & 1u);   // round-to-nearest-even
  return (unsigned short)(u >> 16);
}

// w1 [1024][512] fp32 -> w1t [512][1024] bf16 (transposed so B-frags read contiguous k)
__global__ void k_w1t(const float* __restrict__ w1, unsigned short* __restrict__ w1t) {
  int idx = blockIdx.x * 256 + threadIdx.x;   // exactly 1024*512 threads
  int k = idx >> 9;
  int n = idx & 511;
  w1t[n * 1024 + k] = f2bf(w1[idx]);
}

// C[M,512](bf16) = A[M,512](fp32) @ w1t[:, koff:koff+512]^T   (bf16 MFMA, fp32 acc)
__global__ __launch_bounds__(256) void k_gemm(const float* __restrict__ A, int M,
    const unsigned short* __restrict__ w1t, int koff,
    unsigned short* __restrict__ C)
{
  __shared__ unsigned short As[BM][BKP];
  __shared__ unsigned short Bs[BN][BKP];
  const int tid  = threadIdx.x;
  const int lane = tid & 63;
  const int wid  = tid >> 6;
  const int wm = wid >> 1, wn = wid & 1;      // 2x2 wave grid, 64x64 per wave
  const int lm = lane & 15, lq = lane >> 4;
  const int mbase = blockIdx.x * BM;
  const int nbase = blockIdx.y * BN;

  f32x4 acc[4][4];
  #pragma unroll
  for (int i = 0; i < 4; ++i)
    #pragma unroll
    for (int j = 0; j < 4; ++j) acc[i][j] = (f32x4){0.f, 0.f, 0.f, 0.f};

  for (int kb = 0; kb < HDIM / BK; ++kb) {
    const int k0 = kb * BK;
    __syncthreads();
    // stage A: 128x64 fp32 -> bf16 LDS
    #pragma unroll
    for (int i = 0; i < 8; ++i) {
      int fid = i * 256 + tid;
      int r = fid >> 4, c4 = fid & 15;
      int row = mbase + r; if (row > M - 1) row = M - 1;
      const float4 v = *(const float4*)&A[(size_t)row * HDIM + k0 + c4 * 4];
      ushort4 o; o.x = f2bf(v.x); o.y = f2bf(v.y); o.z = f2bf(v.z); o.w = f2bf(v.w);
      *(ushort4*)&As[r][c4 * 4] = o;
    }
    // stage B: 128x64 bf16
    #pragma unroll
    for (int i = 0; i < 4; ++i) {
      int cid = i * 256 + tid;
      int r = cid >> 3, c8 = cid & 7;
      const ushort4* g = (const ushort4*)&w1t[(size_t)(nbase + r) * 1024 + koff + k0 + c8 * 8];
      ushort4 lo = g[0], hi = g[1];
      *(ushort4*)&Bs[r][c8 * 8]     = lo;
      *(ushort4*)&Bs[r][c8 * 8 + 4] = hi;
    }
    __syncthreads();
    #pragma unroll
    for (int ks = 0; ks < 2; ++ks) {
      bf16x8 af[4], bfr[4];
      #pragma unroll
      for (int t = 0; t < 4; ++t) {
        af[t]  = *(const bf16x8*)&As[wm * 64 + t * 16 + lm][ks * 32 + lq * 8];
        bfr[t] = *(const bf16x8*)&Bs[wn * 64 + t * 16 + lm][ks * 32 + lq * 8];
      }
      #pragma unroll
      for (int mi = 0; mi < 4; ++mi)
        #pragma unroll
        for (int ni = 0; ni < 4; ++ni)
          acc[mi][ni] = __builtin_amdgcn_mfma_f32_16x16x32_bf16(af[mi], bfr[ni], acc[mi][ni], 0, 0, 0);
    }
  }
  // epilogue: C/D layout col=lane&15, row=(lane>>4)*4+reg  (m89-verified)
  #pragma unroll
  for (int mi = 0; mi < 4; ++mi)
    #pragma unroll
    for (int ni = 0; ni < 4; ++ni)
      #pragma unroll
      for (int r = 0; r < 4; ++r) {
        int rg = mbase + wm * 64 + mi * 16 + lq * 4 + r;
        int cg = nbase + wn * 64 + ni * 16 + lm;
        if (rg < M) C[(size_t)rg * HDIM + cg] = f2bf(acc[mi][ni][r]);
      }
}

// per edge: out = relu(U[row]+M[col]+b1) . w2 + b2 ; one wave per edge, grid-stride
__global__ __launch_bounds__(256) void k_edge(const int* __restrict__ er, const int* __restrict__ ec,
    const unsigned short* __restrict__ u1, const unsigned short* __restrict__ m1,
    const float* __restrict__ b1, const float* __restrict__ w2, const float* __restrict__ b2,
    float* __restrict__ out, int E)
{
  const int lane = threadIdx.x & 63;
  const int gwid = blockIdx.x * 4 + (threadIdx.x >> 6);
  const int nw   = gridDim.x * 4;
  const float4 b1a = *(const float4*)&b1[lane * 8];
  const float4 b1b = *(const float4*)&b1[lane * 8 + 4];
  const float4 w2a = *(const float4*)&w2[lane * 8];
  const float4 w2b = *(const float4*)&w2[lane * 8 + 4];
  const float bias2 = b2[0];
  for (int e = gwid; e < E; e += nw) {
    const int r = er[e], c = ec[e];
    const uint4 ua = *(const uint4*)&u1[(size_t)r * HDIM + lane * 8];
    const uint4 va = *(const uint4*)&m1[(size_t)c * HDIM + lane * 8];
    float p = 0.f, s;
    s = __uint_as_float(ua.x << 16)        + __uint_as_float(va.x << 16)        + b1a.x; s = fmaxf(s, 0.f); p += s * w2a.x;
    s = __uint_as_float(ua.x & 0xffff0000u)+ __uint_as_float(va.x & 0xffff0000u)+ b1a.y; s = fmaxf(s, 0.f); p += s * w2a.y;
    s = __uint_as_float(ua.y << 16)        + __uint_as_float(va.y << 16)        + b1a.z; s = fmaxf(s, 0.f); p += s * w2a.z;
    s = __uint_as_float(ua.y & 0xffff0000u)+ __uint_as_float(va.y & 0xffff0000u)+ b1a.w; s = fmaxf(s, 0.f); p += s * w2a.w;
    s = __uint_as_float(ua.z << 16)        + __uint_as_float(va.z << 16)        + b1b.x; s = fmaxf(s, 0.f); p += s * w2b.x;
    s = __uint_as_float(ua.z & 0xffff0000u)+ __uint_as_float(va.z & 0xffff0000u)+ b1b.y; s = fmaxf(s, 0.f); p += s * w2b.y;
    s = __uint_as_float(ua.w << 16)        + __uint_as_float(va.w << 16)        + b1b.z; s = fmaxf(s, 0.f); p += s * w2b.z;
    s = __uint_as_float(ua.w & 0xffff0000u)+ __uint_as_float(va.w & 0xffff0000u)+ b1b.w; s = fmaxf(s, 0.f); p += s * w2b.w;
    #pragma unroll
    for (int off = 32; off > 0; off >>= 1) p += __shfl_down(p, off, 64);
    if (lane == 0) out[e] = p + bias2;
  }
}

// Correct-but-slow fp32 fallback (only if ws_size too small): fused tiled GEMM
__global__ __launch_bounds__(256) void k_fallback(const float* __restrict__ zu, const float* __restrict__ zm,
    const int* __restrict__ er, const int* __restrict__ ec, const float* __restrict__ w1,
    const float* __restrict__ b1, const float* __restrict__ w2, const float* __restrict__ b2,
    float* __restrict__ out, int E)
{
  __shared__ float Zs[64][33];
  __shared__ float Ws[32][65];
  __shared__ float outacc[64];
  __shared__ int ridx[64], cidx[64];
  const int tid = threadIdx.x;
  const int ebase = blockIdx.x * 64;
  if (tid < 64) {
    int e = ebase + tid; if (e > E - 1) e = E - 1;
    ridx[tid] = er[e]; cidx[tid] = ec[e];
    outacc[tid] = 0.f;
  }
  const int tx = tid & 15, ty = tid >> 4;
  for (int nt = 0; nt < 8; ++nt) {
    float acc[4][4] = {};
    for (int kc = 0; kc < 32; ++kc) {
      __syncthreads();
      #pragma unroll
      for (int i = 0; i < 8; ++i) {
        int id = i * 256 + tid;
        int rr = id >> 5, cc = id & 31;
        int k = kc * 32 + cc;
        Zs[rr][cc] = (k < 512) ? zu[(size_t)ridx[rr] * 512 + k]
                               : zm[(size_t)cidx[rr] * 512 + (k - 512)];
      }
      #pragma unroll
      for (int i = 0; i < 8; ++i) {
        int id = i * 256 + tid;
        int kk = id >> 6, nn = id & 63;
        Ws[kk][nn] = w1[(size_t)(kc * 32 + kk) * 512 + nt * 64 + nn];
      }
      __syncthreads();
      #pragma unroll
      for (int kk = 0; kk < 32; ++kk) {
        float a0 = Zs[ty*4+0][kk], a1 = Zs[ty*4+1][kk], a2 = Zs[ty*4+2][kk], a3 = Zs[ty*4+3][kk];
        float q0 = Ws[kk][tx*4+0], q1 = Ws[kk][tx*4+1], q2 = Ws[kk][tx*4+2], q3 = Ws[kk][tx*4+3];
        acc[0][0] += a0*q0; acc[0][1] += a0*q1; acc[0][2] += a0*q2; acc[0][3] += a0*q3;
        acc[1][0] += a1*q0; acc[1][1] += a1*q1; acc[1][2] += a1*q2; acc[1][3] += a1*q3;
        acc[2][0] += a2*q0; acc[2][1] += a2*q1; acc[2][2] += a2*q2; acc[2][3] += a2*q3;
        acc[3][0] += a3*q0; acc[3][1] += a3*q1; acc[3][2] += a3*q2; acc[3][3] += a3*q3;
      }
    }
    #pragma unroll
    for (int i = 0; i < 4; ++i) {
      float p = 0.f;
      #pragma unroll
      for (int j = 0; j < 4; ++j) {
        int n = nt * 64 + tx * 4 + j;
        float h = acc[i][j] + b1[n]; h = fmaxf(h, 0.f);
        p += h * w2[n];
      }
      atomicAdd(&outacc[ty * 4 + i], p);
    }
  }
  __syncthreads();
  if (tid < 64 && (ebase + tid) < E) out[ebase + tid] = outacc[tid] + b2[0];
}

extern "C" void kernel_launch(void* const* d_in, const int* in_sizes, int n_in,
                              void* d_out, int out_size, void* d_ws, size_t ws_size,
                              hipStream_t stream)
{
  const float* z_user  = (const float*)d_in[0];
  const float* z_movie = (const float*)d_in[1];
  const int*   erow    = (const int*)d_in[2];
  const int*   ecol    = (const int*)d_in[3];
  const float* w1      = (const float*)d_in[4];
  const float* b1      = (const float*)d_in[5];
  const float* w2      = (const float*)d_in[6];
  const float* b2      = (const float*)d_in[7];
  float* out = (float*)d_out;

  const int NU = in_sizes[0] / HDIM;   // 100000
  const int NM = in_sizes[1] / HDIM;   // 50000
  const int E  = in_sizes[2];          // 500000

  const size_t need = ((size_t)NU * HDIM + (size_t)NM * HDIM + (size_t)1024 * 512) * 2;
  if (ws_size >= need) {
    unsigned short* u1  = (unsigned short*)d_ws;
    unsigned short* m1  = u1 + (size_t)NU * HDIM;
    unsigned short* w1t = m1 + (size_t)NM * HDIM;
    k_w1t<<<(1024 * 512) / 256, 256, 0, stream>>>(w1, w1t);
    k_gemm<<<dim3((NU + BM - 1) / BM, HDIM / BN), 256, 0, stream>>>(z_user,  NU, w1t, 0,   u1);
    k_gemm<<<dim3((NM + BM - 1) / BM, HDIM / BN), 256, 0, stream>>>(z_movie, NM, w1t, 512, m1);
    k_edge<<<2048, 256, 0, stream>>>(erow, ecol, u1, m1, b1, w2, b2, out, E);
  } else {
    k_fallback<<<(E + 63) / 64, 256, 0, stream>>>(z_user, z_movie, erow, ecol, w1, b1, w2, b2, out, E);
  }
}

// Round 2
// 594.570 us; speedup vs baseline: 1.1036x; 1.1036x over previous
//
#include <hip/hip_runtime.h>
#include <hip/hip_bf16.h>

typedef __attribute__((ext_vector_type(8))) short bf16x8;
typedef __attribute__((ext_vector_type(4))) float f32x4;

#define HDIM 512
#define BM 128
#define BN 256
#define BK 64
#define BKP 72   // +8 bf16 pad -> row stride 144 B (16B-aligned, even 8-group spread for b128)

__device__ __forceinline__ unsigned short f2bf(float f) {
  unsigned u = __float_as_uint(f);
  u += 0x7fffu + ((u >> 16) & 1u);   // round-to-nearest-even
  return (unsigned short)(u >> 16);
}

__device__ __forceinline__ unsigned int pk_bf(float x, float y) {
  __hip_bfloat162 h = __float22bfloat162_rn(float2{x, y});
  union { __hip_bfloat162 b; unsigned int u; } cv; cv.b = h;
  return cv.u;
}

// w1 [1024][512] fp32 -> w1t [512][1024] bf16 (transposed so B-frags read contiguous k)
__global__ void k_w1t(const float* __restrict__ w1, unsigned short* __restrict__ w1t) {
  int idx = blockIdx.x * 256 + threadIdx.x;   // exactly 1024*512 threads
  int k = idx >> 9;
  int n = idx & 511;
  w1t[n * 1024 + k] = f2bf(w1[idx]);
}

// C[M,512](bf16) = A[M,512](fp32) @ w1t[:, koff:koff+512]^T   (bf16 MFMA, fp32 acc)
// 512 threads = 8 waves in a 2(M) x 4(N) grid; each wave owns 64x64 of the 128x256 tile.
__global__ __launch_bounds__(512) void k_gemm(const float* __restrict__ A, int M,
    const unsigned short* __restrict__ w1t, int koff,
    unsigned short* __restrict__ C)
{
  __shared__ unsigned short As[BM][BKP];   // 18 KB
  __shared__ unsigned short Bs[BN][BKP];   // 36 KB
  const int tid  = threadIdx.x;
  const int lane = tid & 63;
  const int wid  = tid >> 6;                  // 0..7
  const int wm = wid & 1, wn = wid >> 1;      // 2 x 4 wave grid
  const int lm = lane & 15, lq = lane >> 4;
  const int nbase = blockIdx.x * BN;          // N-blocks fastest (2 of them)
  const int mbase = blockIdx.y * BM;

  f32x4 acc[4][4];
  #pragma unroll
  for (int i = 0; i < 4; ++i)
    #pragma unroll
    for (int j = 0; j < 4; ++j) acc[i][j] = (f32x4){0.f, 0.f, 0.f, 0.f};

  for (int kb = 0; kb < HDIM / BK; ++kb) {
    const int k0 = kb * BK;
    __syncthreads();
    // stage A: 128x64 fp32 -> bf16 LDS (packed RNE converts)
    #pragma unroll
    for (int i = 0; i < 4; ++i) {
      int fid = i * 512 + tid;
      int r = fid >> 4, c4 = fid & 15;
      int row = mbase + r; if (row > M - 1) row = M - 1;
      const float4 v = *(const float4*)&A[(size_t)row * HDIM + k0 + c4 * 4];
      unsigned int* dst = (unsigned int*)&As[r][c4 * 4];
      dst[0] = pk_bf(v.x, v.y);
      dst[1] = pk_bf(v.z, v.w);
    }
    // stage B: 256x64 bf16, 16B loads/stores
    #pragma unroll
    for (int i = 0; i < 4; ++i) {
      int cid = i * 512 + tid;
      int r = cid >> 3, c8 = cid & 7;
      const bf16x8 g = *(const bf16x8*)&w1t[(size_t)(nbase + r) * 1024 + koff + k0 + c8 * 8];
      *(bf16x8*)&Bs[r][c8 * 8] = g;
    }
    __syncthreads();
    #pragma unroll
    for (int ks = 0; ks < 2; ++ks) {
      bf16x8 af[4], bfr[4];
      #pragma unroll
      for (int t = 0; t < 4; ++t) {
        af[t]  = *(const bf16x8*)&As[wm * 64 + t * 16 + lm][ks * 32 + lq * 8];
        bfr[t] = *(const bf16x8*)&Bs[wn * 64 + t * 16 + lm][ks * 32 + lq * 8];
      }
      #pragma unroll
      for (int mi = 0; mi < 4; ++mi)
        #pragma unroll
        for (int ni = 0; ni < 4; ++ni)
          acc[mi][ni] = __builtin_amdgcn_mfma_f32_16x16x32_bf16(af[mi], bfr[ni], acc[mi][ni], 0, 0, 0);
    }
  }
  // epilogue: C/D layout col=lane&15, row=(lane>>4)*4+reg  (m89-verified)
  #pragma unroll
  for (int mi = 0; mi < 4; ++mi)
    #pragma unroll
    for (int ni = 0; ni < 4; ++ni)
      #pragma unroll
      for (int r = 0; r < 4; ++r) {
        int rg = mbase + wm * 64 + mi * 16 + lq * 4 + r;
        int cg = nbase + wn * 64 + ni * 16 + lm;
        if (rg < M) C[(size_t)rg * HDIM + cg] = f2bf(acc[mi][ni][r]);
      }
}

// per edge: out = relu(U[row]+M[col]+b1) . w2 + b2 ; one wave per edge, 2 edges/iter
__global__ __launch_bounds__(256) void k_edge(const int* __restrict__ er, const int* __restrict__ ec,
    const unsigned short* __restrict__ u1, const unsigned short* __restrict__ m1,
    const float* __restrict__ b1, const float* __restrict__ w2, const float* __restrict__ b2,
    float* __restrict__ out, int E)
{
  const int lane = threadIdx.x & 63;
  const int gwid = blockIdx.x * 4 + (threadIdx.x >> 6);
  const int nw   = gridDim.x * 4;
  const float4 b1a = *(const float4*)&b1[lane * 8];
  const float4 b1b = *(const float4*)&b1[lane * 8 + 4];
  const float4 w2a = *(const float4*)&w2[lane * 8];
  const float4 w2b = *(const float4*)&w2[lane * 8 + 4];
  const float bias2 = b2[0];
  // E is even; e starts even so e+1 < E always holds when e < E.
  for (int e = gwid * 2; e < E; e += nw * 2) {
    const int r0 = er[e], c0 = ec[e];
    const int r1 = er[e + 1], c1 = ec[e + 1];
    const uint4 ua0 = *(const uint4*)&u1[(size_t)r0 * HDIM + lane * 8];
    const uint4 va0 = *(const uint4*)&m1[(size_t)c0 * HDIM + lane * 8];
    const uint4 ua1 = *(const uint4*)&u1[(size_t)r1 * HDIM + lane * 8];
    const uint4 va1 = *(const uint4*)&m1[(size_t)c1 * HDIM + lane * 8];
    float p0 = 0.f, p1 = 0.f, s;
    s = __uint_as_float(ua0.x << 16)        + __uint_as_float(va0.x << 16)        + b1a.x; s = fmaxf(s, 0.f); p0 += s * w2a.x;
    s = __uint_as_float(ua0.x & 0xffff0000u)+ __uint_as_float(va0.x & 0xffff0000u)+ b1a.y; s = fmaxf(s, 0.f); p0 += s * w2a.y;
    s = __uint_as_float(ua0.y << 16)        + __uint_as_float(va0.y << 16)        + b1a.z; s = fmaxf(s, 0.f); p0 += s * w2a.z;
    s = __uint_as_float(ua0.y & 0xffff0000u)+ __uint_as_float(va0.y & 0xffff0000u)+ b1a.w; s = fmaxf(s, 0.f); p0 += s * w2a.w;
    s = __uint_as_float(ua0.z << 16)        + __uint_as_float(va0.z << 16)        + b1b.x; s = fmaxf(s, 0.f); p0 += s * w2b.x;
    s = __uint_as_float(ua0.z & 0xffff0000u)+ __uint_as_float(va0.z & 0xffff0000u)+ b1b.y; s = fmaxf(s, 0.f); p0 += s * w2b.y;
    s = __uint_as_float(ua0.w << 16)        + __uint_as_float(va0.w << 16)        + b1b.z; s = fmaxf(s, 0.f); p0 += s * w2b.z;
    s = __uint_as_float(ua0.w & 0xffff0000u)+ __uint_as_float(va0.w & 0xffff0000u)+ b1b.w; s = fmaxf(s, 0.f); p0 += s * w2b.w;
    s = __uint_as_float(ua1.x << 16)        + __uint_as_float(va1.x << 16)        + b1a.x; s = fmaxf(s, 0.f); p1 += s * w2a.x;
    s = __uint_as_float(ua1.x & 0xffff0000u)+ __uint_as_float(va1.x & 0xffff0000u)+ b1a.y; s = fmaxf(s, 0.f); p1 += s * w2a.y;
    s = __uint_as_float(ua1.y << 16)        + __uint_as_float(va1.y << 16)        + b1a.z; s = fmaxf(s, 0.f); p1 += s * w2a.z;
    s = __uint_as_float(ua1.y & 0xffff0000u)+ __uint_as_float(va1.y & 0xffff0000u)+ b1a.w; s = fmaxf(s, 0.f); p1 += s * w2a.w;
    s = __uint_as_float(ua1.z << 16)        + __uint_as_float(va1.z << 16)        + b1b.x; s = fmaxf(s, 0.f); p1 += s * w2b.x;
    s = __uint_as_float(ua1.z & 0xffff0000u)+ __uint_as_float(va1.z & 0xffff0000u)+ b1b.y; s = fmaxf(s, 0.f); p1 += s * w2b.y;
    s = __uint_as_float(ua1.w << 16)        + __uint_as_float(va1.w << 16)        + b1b.z; s = fmaxf(s, 0.f); p1 += s * w2b.z;
    s = __uint_as_float(ua1.w & 0xffff0000u)+ __uint_as_float(va1.w & 0xffff0000u)+ b1b.w; s = fmaxf(s, 0.f); p1 += s * w2b.w;
    #pragma unroll
    for (int off = 32; off > 0; off >>= 1) {
      p0 += __shfl_down(p0, off, 64);
      p1 += __shfl_down(p1, off, 64);
    }
    if (lane == 0) *(float2*)&out[e] = float2{p0 + bias2, p1 + bias2};
  }
}

// Correct-but-slow fp32 fallback (only if ws_size too small): fused tiled GEMM
__global__ __launch_bounds__(256) void k_fallback(const float* __restrict__ zu, const float* __restrict__ zm,
    const int* __restrict__ er, const int* __restrict__ ec, const float* __restrict__ w1,
    const float* __restrict__ b1, const float* __restrict__ w2, const float* __restrict__ b2,
    float* __restrict__ out, int E)
{
  __shared__ float Zs[64][33];
  __shared__ float Ws[32][65];
  __shared__ float outacc[64];
  __shared__ int ridx[64], cidx[64];
  const int tid = threadIdx.x;
  const int ebase = blockIdx.x * 64;
  if (tid < 64) {
    int e = ebase + tid; if (e > E - 1) e = E - 1;
    ridx[tid] = er[e]; cidx[tid] = ec[e];
    outacc[tid] = 0.f;
  }
  const int tx = tid & 15, ty = tid >> 4;
  for (int nt = 0; nt < 8; ++nt) {
    float acc[4][4] = {};
    for (int kc = 0; kc < 32; ++kc) {
      __syncthreads();
      #pragma unroll
      for (int i = 0; i < 8; ++i) {
        int id = i * 256 + tid;
        int rr = id >> 5, cc = id & 31;
        int k = kc * 32 + cc;
        Zs[rr][cc] = (k < 512) ? zu[(size_t)ridx[rr] * 512 + k]
                               : zm[(size_t)cidx[rr] * 512 + (k - 512)];
      }
      #pragma unroll
      for (int i = 0; i < 8; ++i) {
        int id = i * 256 + tid;
        int kk = id >> 6, nn = id & 63;
        Ws[kk][nn] = w1[(size_t)(kc * 32 + kk) * 512 + nt * 64 + nn];
      }
      __syncthreads();
      #pragma unroll
      for (int kk = 0; kk < 32; ++kk) {
        float a0 = Zs[ty*4+0][kk], a1 = Zs[ty*4+1][kk], a2 = Zs[ty*4+2][kk], a3 = Zs[ty*4+3][kk];
        float q0 = Ws[kk][tx*4+0], q1 = Ws[kk][tx*4+1], q2 = Ws[kk][tx*4+2], q3 = Ws[kk][tx*4+3];
        acc[0][0] += a0*q0; acc[0][1] += a0*q1; acc[0][2] += a0*q2; acc[0][3] += a0*q3;
        acc[1][0] += a1*q0; acc[1][1] += a1*q1; acc[1][2] += a1*q2; acc[1][3] += a1*q3;
        acc[2][0] += a2*q0; acc[2][1] += a2*q1; acc[2][2] += a2*q2; acc[2][3] += a2*q3;
        acc[3][0] += a3*q0; acc[3][1] += a3*q1; acc[3][2] += a3*q2; acc[3][3] += a3*q3;
      }
    }
    #pragma unroll
    for (int i = 0; i < 4; ++i) {
      float p = 0.f;
      #pragma unroll
      for (int j = 0; j < 4; ++j) {
        int n = nt * 64 + tx * 4 + j;
        float h = acc[i][j] + b1[n]; h = fmaxf(h, 0.f);
        p += h * w2[n];
      }
      atomicAdd(&outacc[ty * 4 + i], p);
    }
  }
  __syncthreads();
  if (tid < 64 && (ebase + tid) < E) out[ebase + tid] = outacc[tid] + b2[0];
}

extern "C" void kernel_launch(void* const* d_in, const int* in_sizes, int n_in,
                              void* d_out, int out_size, void* d_ws, size_t ws_size,
                              hipStream_t stream)
{
  const float* z_user  = (const float*)d_in[0];
  const float* z_movie = (const float*)d_in[1];
  const int*   erow    = (const int*)d_in[2];
  const int*   ecol    = (const int*)d_in[3];
  const float* w1      = (const float*)d_in[4];
  const float* b1      = (const float*)d_in[5];
  const float* w2      = (const float*)d_in[6];
  const float* b2      = (const float*)d_in[7];
  float* out = (float*)d_out;

  const int NU = in_sizes[0] / HDIM;   // 100000
  const int NM = in_sizes[1] / HDIM;   // 50000
  const int E  = in_sizes[2];          // 500000

  const size_t need = ((size_t)NU * HDIM + (size_t)NM * HDIM + (size_t)1024 * 512) * 2;
  if (ws_size >= need) {
    unsigned short* u1  = (unsigned short*)d_ws;
    unsigned short* m1  = u1 + (size_t)NU * HDIM;
    unsigned short* w1t = m1 + (size_t)NM * HDIM;
    k_w1t<<<(1024 * 512) / 256, 256, 0, stream>>>(w1, w1t);
    k_gemm<<<dim3(HDIM / BN, (NU + BM - 1) / BM), 512, 0, stream>>>(z_user,  NU, w1t, 0,   u1);
    k_gemm<<<dim3(HDIM / BN, (NM + BM - 1) / BM), 512, 0, stream>>>(z_movie, NM, w1t, 512, m1);
    k_edge<<<2048, 256, 0, stream>>>(erow, ecol, u1, m1, b1, w2, b2, out, E);
  } else {
    k_fallback<<<(E + 63) / 64, 256, 0, stream>>>(z_user, z_movie, erow, ecol, w1, b1, w2, b2, out, E);
  }
}